// Round 7
// baseline (272.161 us; speedup 1.0000x reference)
//
#include <hip/hip_runtime.h>

// MLSA-style multi-stage time-varying FIR.
// y = (sum_{n=0..20} F^n x / n!) * exp(lerp(mc[...,0]))
// F: xn[t] = sum_{d=1..49} lerp_t(mc[:, :, d]) * xa[t-d]
//
// Round-6: single change vs the proven 80us structure (R2/R4): ALL 25 tap
// float4s {c_d, dc_d} live in registers (NTC=25, ~+60 VGPR over R4's 84,
// under the 170 cap at 3 waves/SIMD). Per-stage LDS drops to 13 window
// reads + 2 stores per thread. Straight-line code shape only -- round 5's
// JIT-interleaved loads made the compiler demote A[]/tr[] to scratch
// (FETCH 535MB); no conditional loads inside the tap loop.

#define FO    49      // filter order (lags 1..49)
#define FP    80      // frame period
#define NST   20      // Taylor stages
#define NB    8       // batch
#define TT    160000  // samples per batch row
#define NFR   2000    // frames
#define NC    50      // coeffs per frame
#define HALO  1024    // left halo (>= 20*49=980)
#define NT    768     // threads per block (12 waves)
#define RPT   8       // samples per thread (8 | 80 -> thread stays in 1 frame)
#define EE    6144    // NT*RPT extended region
#define TOUT  5120    // EE - HALO outputs per tile
#define TILES 32      // TT / TOUT coverage (32*5120 = 163840 >= 160000)
#define PADW  56      // zero pad words in front of data (underrun reach: 52)
#define NFRL  78      // tap rows per block
#define TROW  100     // tap row stride in words (49 float2 + pad; 400B)

// 16B-group XOR swizzle. NOTE: swz(g+1) != swz(g)+1 in odd octets -- always
// swizzle each group address individually (round-3 bug).
__device__ __forceinline__ int swz(int g) { return g ^ ((g >> 3) & 7); }

__global__ __launch_bounds__(NT, 3) void mlsa_kernel(
    const float* __restrict__ x, const float* __restrict__ mc,
    float* __restrict__ out) {
  __shared__ __align__(16) float sb0[PADW + EE];
  __shared__ __align__(16) float sb1[PADW + EE];
  __shared__ __align__(16) float taps[NFRL * TROW];

  const int tid  = threadIdx.x;
  const int b    = blockIdx.x >> 5;   // TILES == 32
  const int tile = blockIdx.x & 31;
  const int base = tile * TOUT - HALO;  // global sample index of local 0
  const float* __restrict__ xb  = x + b * TT;
  const float* __restrict__ mcb = mc + b * NFR * NC;

  if (tid < PADW) { sb0[tid] = 0.f; sb1[tid] = 0.f; }

  // Stage x tile into sb0 (stride-1 groups, coalesced; base%4==0, TT%4==0).
  #pragma unroll
  for (int i = 0; i < EE / 4 / NT; ++i) {
    const int q  = i * NT + tid;
    const int t0 = base + q * 4;
    float4 v = make_float4(0.f, 0.f, 0.f, 0.f);
    if (t0 >= 0 && t0 < TT) v = *(const float4*)(xb + t0);
    *(float4*)(sb0 + PADW + 4 * swz(q)) = v;
  }

  // Tap table -> LDS. Row e = frame fb+e; word 2*(d-1) = {c_d, dc_d/FP}.
  const int fb = max(base, 0) / FP;
  for (int idx = tid; idx < NFRL * FO; idx += NT) {
    const int e  = idx / FO;
    const int dm = idx - e * FO;
    const int fa = min(fb + e, NFR - 1);
    const int fn = min(fb + e + 1, NFR - 1);
    const float a0 = mcb[fa * NC + dm + 1];
    const float a1 = mcb[fn * NC + dm + 1];
    *(float2*)(taps + e * TROW + 2 * dm) = make_float2(a0, (a1 - a0) * (1.0f / FP));
  }

  // Flat map: thread owns samples 8*tid .. 8*tid+7 (one frame: 8|80).
  const int g0 = base + RPT * tid;
  const int gc = min(max(g0, 0), TT - 1);
  const int n0 = gc / FP;
  const int fi = n0 - fb;
  const float p0f = (float)(gc - n0 * FP);

  // Window LDS group addresses (each swizzled individually): groups
  // 2*tid-13 .. 2*tid-1 cover words 8*tid-52 .. 8*tid-1; q<0 -> pad region.
  int widx[13];
  #pragma unroll
  for (int i = 0; i < 13; ++i) {
    const int q = 2 * tid - 13 + i;
    widx[i] = (q < 0) ? (PADW + 4 * q) : (PADW + 4 * swz(q));
  }
  const int sidx0 = PADW + 4 * swz(2 * tid);
  const int sidx1 = PADW + 4 * swz(2 * tid + 1);

  // Own 8 samples; xp persists across stages (= prev stage values).
  float xp[RPT];
  #pragma unroll
  for (int k = 0; k < 2; ++k) {
    const int t0 = g0 + 4 * k;
    float4 v = make_float4(0.f, 0.f, 0.f, 0.f);
    if (t0 >= 0 && t0 < TT) v = *(const float4*)(xb + t0);
    xp[4*k] = v.x; xp[4*k+1] = v.y; xp[4*k+2] = v.z; xp[4*k+3] = v.w;
  }
  float y[RPT];
  #pragma unroll
  for (int j = 0; j < RPT; ++j) y[j] = xp[j];

  __syncthreads();

  // FULL register tap cache: lags 1..49 ({c,dc} pairs; slot d=50 is dummy).
  const float* trow = taps + fi * TROW;
  float4 tr[25];
  #pragma unroll
  for (int p = 0; p < 25; ++p) tr[p] = *(const float4*)(trow + 4 * p);

  const float* rb = sb0;
  float*       wb = sb1;
  #pragma unroll 1
  for (int s = 1; s <= NST; ++s) {
    // A[m] = stage-(s-1) value at word 8*tid-52+m, m = 0..51; own 8 in xp.
    float A[52];
    #pragma unroll
    for (int i = 0; i < 13; ++i) {
      const float4 v = *(const float4*)(rb + widx[i]);
      A[4*i] = v.x; A[4*i+1] = v.y; A[4*i+2] = v.z; A[4*i+3] = v.w;
    }
    float acc0[RPT], acc1[RPT];
    #pragma unroll
    for (int j = 0; j < RPT; ++j) { acc0[j] = 0.f; acc1[j] = 0.f; }
    #pragma unroll
    for (int p = 0; p < 25; ++p) {
      const float4 tp = tr[p];
      const int d0 = 2 * p + 1, d1 = 2 * p + 2;
      #pragma unroll
      for (int j = 0; j < RPT; ++j) {
        const int ka = 52 + j - d0;
        const float va = (ka < 52) ? A[ka] : xp[ka - 52];
        acc0[j] = fmaf(tp.x, va, acc0[j]);
        acc1[j] = fmaf(tp.y, va, acc1[j]);
        if (d1 <= FO) {                    // d1==50 slot is a dummy
          const int kb = 52 + j - d1;
          const float vb = (kb < 52) ? A[kb] : xp[kb - 52];
          acc0[j] = fmaf(tp.z, vb, acc0[j]);
          acc1[j] = fmaf(tp.w, vb, acc1[j]);
        }
      }
    }
    const float ia = 1.0f / (float)s;
    #pragma unroll
    for (int j = 0; j < RPT; ++j) {
      const float xn = fmaf(p0f + (float)j, acc1[j], acc0[j]) * ia;
      y[j] += xn;
      xp[j] = xn;
    }
    {
      float4 v;
      v.x = xp[0]; v.y = xp[1]; v.z = xp[2]; v.w = xp[3];
      *(float4*)(wb + sidx0) = v;
      v.x = xp[4]; v.y = xp[5]; v.z = xp[6]; v.w = xp[7];
      *(float4*)(wb + sidx1) = v;
    }
    __syncthreads();
    const float* t = rb; rb = wb; wb = (float*)t;
  }

  // Epilogue: out = y * exp(lerp(mc[...,0])). Outputs are samples >= HALO.
  if (tid >= HALO / RPT && g0 < TT) {
    const int n1 = min(n0 + 1, NFR - 1);
    const float k0 = mcb[n0 * NC];
    const float k1 = mcb[n1 * NC];
    const float dk = (k1 - k0) * (1.0f / FP);
    float* ob = out + b * TT + g0;
    #pragma unroll
    for (int k = 0; k < 2; ++k) {
      float4 v;
      #pragma unroll
      for (int e = 0; e < 4; ++e) {
        const int j = 4 * k + e;
        const float Kg = __expf(fmaf(p0f + (float)j, dk, k0));
        ((float*)&v)[e] = y[j] * Kg;
      }
      *(float4*)(ob + 4 * k) = v;
    }
  }
}

extern "C" void kernel_launch(void* const* d_in, const int* in_sizes, int n_in,
                              void* d_out, int out_size, void* d_ws, size_t ws_size,
                              hipStream_t stream) {
  const float* x  = (const float*)d_in[0];
  const float* mc = (const float*)d_in[1];
  float* out      = (float*)d_out;
  mlsa_kernel<<<NB * TILES, NT, 0, stream>>>(x, mc, out);
}

// Round 8
// 223.235 us; speedup vs baseline: 1.2192x; 1.2192x over previous
//
#include <hip/hip_runtime.h>

// MLSA-style multi-stage time-varying FIR.
// y = (sum_{n=0..20} F^n x / n!) * exp(lerp(mc[...,0]))
// F: xn[t] = sum_{d=1..49} lerp_t(mc[:, :, d]) * xa[t-d]
//
// Round-7: same hypothesis as R5/R6 (cut per-stage tap LDS traffic), with
// WORKING codegen. R5/R6 failed because tr[20]/tr[25] float4 ARRAYS exceed
// the promote-alloca limit -> demoted to scratch (FETCH 535/783 MB, VGPR
// pinned at 84). Taps for lags 1..40 now live in 20 individually-NAMED
// float4 SSA values (no alloca, nothing to demote). Lags 41..49 read from
// LDS per stage (5 float4). Per-thread LDS/stage: 30 -> 20 wave-inst.
// Everything else identical to the proven 80us R2/R4 structure.

#define FO    49      // filter order (lags 1..49)
#define FP    80      // frame period
#define NST   20      // Taylor stages
#define NB    8       // batch
#define TT    160000  // samples per batch row
#define NFR   2000    // frames
#define NC    50      // coeffs per frame
#define HALO  1024    // left halo (>= 20*49=980)
#define NT    768     // threads per block (12 waves)
#define RPT   8       // samples per thread (8 | 80 -> thread stays in 1 frame)
#define EE    6144    // NT*RPT extended region
#define TOUT  5120    // EE - HALO outputs per tile
#define TILES 32      // TT / TOUT coverage (32*5120 = 163840 >= 160000)
#define PADW  56      // zero pad words in front of data (underrun reach: 52)
#define NFRL  78      // tap rows per block
#define TROW  100     // tap row stride in words (49 float2 + pad; 400B)

// 16B-group XOR swizzle. NOTE: swz(g+1) != swz(g)+1 in odd octets -- always
// swizzle each group address individually (round-3 bug).
__device__ __forceinline__ int swz(int g) { return g ^ ((g >> 3) & 7); }

// One tap pair (lags d0=2*PP+1, d1=2*PP+2) applied to all RPT samples.
// PP must be a compile-time literal; branches fold under unroll.
#define TAPSTEP(PP, TP)                                                \
  {                                                                    \
    const int d0 = 2 * (PP) + 1, d1 = 2 * (PP) + 2;                    \
    _Pragma("unroll")                                                  \
    for (int j = 0; j < RPT; ++j) {                                    \
      const int ka = 52 + j - d0;                                      \
      const float va = (ka < 52) ? A[ka] : xp[ka - 52];                \
      acc0[j] = fmaf((TP).x, va, acc0[j]);                             \
      acc1[j] = fmaf((TP).y, va, acc1[j]);                             \
      if (d1 <= FO) {                                                  \
        const int kb = 52 + j - d1;                                    \
        const float vb = (kb < 52) ? A[kb] : xp[kb - 52];              \
        acc0[j] = fmaf((TP).z, vb, acc0[j]);                           \
        acc1[j] = fmaf((TP).w, vb, acc1[j]);                           \
      }                                                                \
    }                                                                  \
  }

__global__ __launch_bounds__(NT, 3) void mlsa_kernel(
    const float* __restrict__ x, const float* __restrict__ mc,
    float* __restrict__ out) {
  __shared__ __align__(16) float sb0[PADW + EE];
  __shared__ __align__(16) float sb1[PADW + EE];
  __shared__ __align__(16) float taps[NFRL * TROW];

  const int tid  = threadIdx.x;
  const int b    = blockIdx.x >> 5;   // TILES == 32
  const int tile = blockIdx.x & 31;
  const int base = tile * TOUT - HALO;  // global sample index of local 0
  const float* __restrict__ xb  = x + b * TT;
  const float* __restrict__ mcb = mc + b * NFR * NC;

  if (tid < PADW) { sb0[tid] = 0.f; sb1[tid] = 0.f; }

  // Stage x tile into sb0 (stride-1 groups, coalesced; base%4==0, TT%4==0).
  #pragma unroll
  for (int i = 0; i < EE / 4 / NT; ++i) {
    const int q  = i * NT + tid;
    const int t0 = base + q * 4;
    float4 v = make_float4(0.f, 0.f, 0.f, 0.f);
    if (t0 >= 0 && t0 < TT) v = *(const float4*)(xb + t0);
    *(float4*)(sb0 + PADW + 4 * swz(q)) = v;
  }

  // Tap table -> LDS. Row e = frame fb+e; word 2*(d-1) = {c_d, dc_d/FP}.
  const int fb = max(base, 0) / FP;
  for (int idx = tid; idx < NFRL * FO; idx += NT) {
    const int e  = idx / FO;
    const int dm = idx - e * FO;
    const int fa = min(fb + e, NFR - 1);
    const int fn = min(fb + e + 1, NFR - 1);
    const float a0 = mcb[fa * NC + dm + 1];
    const float a1 = mcb[fn * NC + dm + 1];
    *(float2*)(taps + e * TROW + 2 * dm) = make_float2(a0, (a1 - a0) * (1.0f / FP));
  }

  // Flat map: thread owns samples 8*tid .. 8*tid+7 (one frame: 8|80).
  const int g0 = base + RPT * tid;
  const int gc = min(max(g0, 0), TT - 1);
  const int n0 = gc / FP;
  const int fi = n0 - fb;
  const float p0f = (float)(gc - n0 * FP);

  // Window LDS group addresses (each swizzled individually): groups
  // 2*tid-13 .. 2*tid-1 cover words 8*tid-52 .. 8*tid-1; q<0 -> pad region.
  int widx[13];
  #pragma unroll
  for (int i = 0; i < 13; ++i) {
    const int q = 2 * tid - 13 + i;
    widx[i] = (q < 0) ? (PADW + 4 * q) : (PADW + 4 * swz(q));
  }
  const int sidx0 = PADW + 4 * swz(2 * tid);
  const int sidx1 = PADW + 4 * swz(2 * tid + 1);

  // Own 8 samples; xp persists across stages (= prev stage values).
  float xp[RPT];
  #pragma unroll
  for (int k = 0; k < 2; ++k) {
    const int t0 = g0 + 4 * k;
    float4 v = make_float4(0.f, 0.f, 0.f, 0.f);
    if (t0 >= 0 && t0 < TT) v = *(const float4*)(xb + t0);
    xp[4*k] = v.x; xp[4*k+1] = v.y; xp[4*k+2] = v.z; xp[4*k+3] = v.w;
  }
  float y[RPT];
  #pragma unroll
  for (int j = 0; j < RPT; ++j) y[j] = xp[j];

  __syncthreads();

  // Taps for lags 1..40 in 20 NAMED float4s (SSA values -> guaranteed VGPRs;
  // arrays of this size get demoted to scratch, see R5/R6).
  const float* trow = taps + fi * TROW;
  const float4 t00 = *(const float4*)(trow +  0);
  const float4 t01 = *(const float4*)(trow +  4);
  const float4 t02 = *(const float4*)(trow +  8);
  const float4 t03 = *(const float4*)(trow + 12);
  const float4 t04 = *(const float4*)(trow + 16);
  const float4 t05 = *(const float4*)(trow + 20);
  const float4 t06 = *(const float4*)(trow + 24);
  const float4 t07 = *(const float4*)(trow + 28);
  const float4 t08 = *(const float4*)(trow + 32);
  const float4 t09 = *(const float4*)(trow + 36);
  const float4 t10 = *(const float4*)(trow + 40);
  const float4 t11 = *(const float4*)(trow + 44);
  const float4 t12 = *(const float4*)(trow + 48);
  const float4 t13 = *(const float4*)(trow + 52);
  const float4 t14 = *(const float4*)(trow + 56);
  const float4 t15 = *(const float4*)(trow + 60);
  const float4 t16 = *(const float4*)(trow + 64);
  const float4 t17 = *(const float4*)(trow + 68);
  const float4 t18 = *(const float4*)(trow + 72);
  const float4 t19 = *(const float4*)(trow + 76);

  const float* rb = sb0;
  float*       wb = sb1;
  #pragma unroll 1
  for (int s = 1; s <= NST; ++s) {
    // A[m] = stage-(s-1) value at word 8*tid-52+m, m = 0..51; own 8 in xp.
    float A[52];
    #pragma unroll
    for (int i = 0; i < 13; ++i) {
      const float4 v = *(const float4*)(rb + widx[i]);
      A[4*i] = v.x; A[4*i+1] = v.y; A[4*i+2] = v.z; A[4*i+3] = v.w;
    }
    float acc0[RPT], acc1[RPT];
    #pragma unroll
    for (int j = 0; j < RPT; ++j) { acc0[j] = 0.f; acc1[j] = 0.f; }
    // Lags 1..40 from named register taps.
    TAPSTEP(0,  t00) TAPSTEP(1,  t01) TAPSTEP(2,  t02) TAPSTEP(3,  t03)
    TAPSTEP(4,  t04) TAPSTEP(5,  t05) TAPSTEP(6,  t06) TAPSTEP(7,  t07)
    TAPSTEP(8,  t08) TAPSTEP(9,  t09) TAPSTEP(10, t10) TAPSTEP(11, t11)
    TAPSTEP(12, t12) TAPSTEP(13, t13) TAPSTEP(14, t14) TAPSTEP(15, t15)
    TAPSTEP(16, t16) TAPSTEP(17, t17) TAPSTEP(18, t18) TAPSTEP(19, t19)
    // Lags 41..49 from LDS (p compile-time under unroll; d1=50 slot dummy).
    #pragma unroll
    for (int p = 20; p < 25; ++p) {
      const float4 tp = *(const float4*)(trow + 4 * p);
      TAPSTEP(p, tp)
    }
    const float ia = 1.0f / (float)s;
    #pragma unroll
    for (int j = 0; j < RPT; ++j) {
      const float xn = fmaf(p0f + (float)j, acc1[j], acc0[j]) * ia;
      y[j] += xn;
      xp[j] = xn;
    }
    {
      float4 v;
      v.x = xp[0]; v.y = xp[1]; v.z = xp[2]; v.w = xp[3];
      *(float4*)(wb + sidx0) = v;
      v.x = xp[4]; v.y = xp[5]; v.z = xp[6]; v.w = xp[7];
      *(float4*)(wb + sidx1) = v;
    }
    __syncthreads();
    const float* t = rb; rb = wb; wb = (float*)t;
  }

  // Epilogue: out = y * exp(lerp(mc[...,0])). Outputs are samples >= HALO.
  if (tid >= HALO / RPT && g0 < TT) {
    const int n1 = min(n0 + 1, NFR - 1);
    const float k0 = mcb[n0 * NC];
    const float k1 = mcb[n1 * NC];
    const float dk = (k1 - k0) * (1.0f / FP);
    float* ob = out + b * TT + g0;
    #pragma unroll
    for (int k = 0; k < 2; ++k) {
      float4 v;
      #pragma unroll
      for (int e = 0; e < 4; ++e) {
        const int j = 4 * k + e;
        const float Kg = __expf(fmaf(p0f + (float)j, dk, k0));
        ((float*)&v)[e] = y[j] * Kg;
      }
      *(float4*)(ob + 4 * k) = v;
    }
  }
}

extern "C" void kernel_launch(void* const* d_in, const int* in_sizes, int n_in,
                              void* d_out, int out_size, void* d_ws, size_t ws_size,
                              hipStream_t stream) {
  const float* x  = (const float*)d_in[0];
  const float* mc = (const float*)d_in[1];
  float* out      = (float*)d_out;
  mlsa_kernel<<<NB * TILES, NT, 0, stream>>>(x, mc, out);
}

// Round 9
// 212.546 us; speedup vs baseline: 1.2805x; 1.0503x over previous
//
#include <hip/hip_runtime.h>

// MLSA-style multi-stage time-varying FIR.
// y = (sum_{n=0..20} F^n x / n!) * exp(lerp(mc[...,0]))
// F: xn[t] = sum_{d=1..49} lerp_t(mc[:, :, d]) * xa[t-d]
//
// Round-8: ROOT CAUSE of R5/R6/R7 spills found. VGPR_Count was pinned at 84
// = 512/6 for every NT=768 build: LDS was 80896 B, and 2*80896 <= 163840, so
// the compiler assumed 2 blocks/CU (6 waves/SIMD) and capped registers at 84,
// spilling past it (FETCH 535-783 MB). The grid is 1 block/CU, so that
// assumption is pure loss. Fix: pad LDS past 81920 B (NFRL 78 -> 82) so only
// ONE block fits -> register budget ~170. Code otherwise byte-identical to
// R7 (20 named float4 tap regs for lags 1..40, 5 LDS tap reads for 41..49).

#define FO    49      // filter order (lags 1..49)
#define FP    80      // frame period
#define NST   20      // Taylor stages
#define NB    8       // batch
#define TT    160000  // samples per batch row
#define NFR   2000    // frames
#define NC    50      // coeffs per frame
#define HALO  1024    // left halo (>= 20*49=980)
#define NT    768     // threads per block (12 waves)
#define RPT   8       // samples per thread (8 | 80 -> thread stays in 1 frame)
#define EE    6144    // NT*RPT extended region
#define TOUT  5120    // EE - HALO outputs per tile
#define TILES 32      // TT / TOUT coverage (32*5120 = 163840 >= 160000)
#define PADW  56      // zero pad words in front of data (underrun reach: 52)
#define NFRL  82      // tap rows: 78 needed; 82 pads LDS to 82400 B > 81920 B
                      // so only 1 block/CU fits -> VGPR budget 170, not 84.
#define TROW  100     // tap row stride in words (49 float2 + pad; 400B)

// 16B-group XOR swizzle. NOTE: swz(g+1) != swz(g)+1 in odd octets -- always
// swizzle each group address individually (round-3 bug).
__device__ __forceinline__ int swz(int g) { return g ^ ((g >> 3) & 7); }

// One tap pair (lags d0=2*PP+1, d1=2*PP+2) applied to all RPT samples.
// PP must be a compile-time literal; branches fold under unroll.
#define TAPSTEP(PP, TP)                                                \
  {                                                                    \
    const int d0 = 2 * (PP) + 1, d1 = 2 * (PP) + 2;                    \
    _Pragma("unroll")                                                  \
    for (int j = 0; j < RPT; ++j) {                                    \
      const int ka = 52 + j - d0;                                      \
      const float va = (ka < 52) ? A[ka] : xp[ka - 52];                \
      acc0[j] = fmaf((TP).x, va, acc0[j]);                             \
      acc1[j] = fmaf((TP).y, va, acc1[j]);                             \
      if (d1 <= FO) {                                                  \
        const int kb = 52 + j - d1;                                    \
        const float vb = (kb < 52) ? A[kb] : xp[kb - 52];              \
        acc0[j] = fmaf((TP).z, vb, acc0[j]);                           \
        acc1[j] = fmaf((TP).w, vb, acc1[j]);                           \
      }                                                                \
    }                                                                  \
  }

__global__ __launch_bounds__(NT, 3) void mlsa_kernel(
    const float* __restrict__ x, const float* __restrict__ mc,
    float* __restrict__ out) {
  __shared__ __align__(16) float sb0[PADW + EE];
  __shared__ __align__(16) float sb1[PADW + EE];
  __shared__ __align__(16) float taps[NFRL * TROW];

  const int tid  = threadIdx.x;
  const int b    = blockIdx.x >> 5;   // TILES == 32
  const int tile = blockIdx.x & 31;
  const int base = tile * TOUT - HALO;  // global sample index of local 0
  const float* __restrict__ xb  = x + b * TT;
  const float* __restrict__ mcb = mc + b * NFR * NC;

  if (tid < PADW) { sb0[tid] = 0.f; sb1[tid] = 0.f; }

  // Stage x tile into sb0 (stride-1 groups, coalesced; base%4==0, TT%4==0).
  #pragma unroll
  for (int i = 0; i < EE / 4 / NT; ++i) {
    const int q  = i * NT + tid;
    const int t0 = base + q * 4;
    float4 v = make_float4(0.f, 0.f, 0.f, 0.f);
    if (t0 >= 0 && t0 < TT) v = *(const float4*)(xb + t0);
    *(float4*)(sb0 + PADW + 4 * swz(q)) = v;
  }

  // Tap table -> LDS. Row e = frame fb+e; word 2*(d-1) = {c_d, dc_d/FP}.
  const int fb = max(base, 0) / FP;
  for (int idx = tid; idx < NFRL * FO; idx += NT) {
    const int e  = idx / FO;
    const int dm = idx - e * FO;
    const int fa = min(fb + e, NFR - 1);
    const int fn = min(fb + e + 1, NFR - 1);
    const float a0 = mcb[fa * NC + dm + 1];
    const float a1 = mcb[fn * NC + dm + 1];
    *(float2*)(taps + e * TROW + 2 * dm) = make_float2(a0, (a1 - a0) * (1.0f / FP));
  }

  // Flat map: thread owns samples 8*tid .. 8*tid+7 (one frame: 8|80).
  const int g0 = base + RPT * tid;
  const int gc = min(max(g0, 0), TT - 1);
  const int n0 = gc / FP;
  const int fi = n0 - fb;
  const float p0f = (float)(gc - n0 * FP);

  // Window LDS group addresses (each swizzled individually): groups
  // 2*tid-13 .. 2*tid-1 cover words 8*tid-52 .. 8*tid-1; q<0 -> pad region.
  int widx[13];
  #pragma unroll
  for (int i = 0; i < 13; ++i) {
    const int q = 2 * tid - 13 + i;
    widx[i] = (q < 0) ? (PADW + 4 * q) : (PADW + 4 * swz(q));
  }
  const int sidx0 = PADW + 4 * swz(2 * tid);
  const int sidx1 = PADW + 4 * swz(2 * tid + 1);

  // Own 8 samples; xp persists across stages (= prev stage values).
  float xp[RPT];
  #pragma unroll
  for (int k = 0; k < 2; ++k) {
    const int t0 = g0 + 4 * k;
    float4 v = make_float4(0.f, 0.f, 0.f, 0.f);
    if (t0 >= 0 && t0 < TT) v = *(const float4*)(xb + t0);
    xp[4*k] = v.x; xp[4*k+1] = v.y; xp[4*k+2] = v.z; xp[4*k+3] = v.w;
  }
  float y[RPT];
  #pragma unroll
  for (int j = 0; j < RPT; ++j) y[j] = xp[j];

  __syncthreads();

  // Taps for lags 1..40 in 20 NAMED float4s (SSA values -> VGPRs now that
  // the register budget is 170, not 84).
  const float* trow = taps + fi * TROW;
  const float4 t00 = *(const float4*)(trow +  0);
  const float4 t01 = *(const float4*)(trow +  4);
  const float4 t02 = *(const float4*)(trow +  8);
  const float4 t03 = *(const float4*)(trow + 12);
  const float4 t04 = *(const float4*)(trow + 16);
  const float4 t05 = *(const float4*)(trow + 20);
  const float4 t06 = *(const float4*)(trow + 24);
  const float4 t07 = *(const float4*)(trow + 28);
  const float4 t08 = *(const float4*)(trow + 32);
  const float4 t09 = *(const float4*)(trow + 36);
  const float4 t10 = *(const float4*)(trow + 40);
  const float4 t11 = *(const float4*)(trow + 44);
  const float4 t12 = *(const float4*)(trow + 48);
  const float4 t13 = *(const float4*)(trow + 52);
  const float4 t14 = *(const float4*)(trow + 56);
  const float4 t15 = *(const float4*)(trow + 60);
  const float4 t16 = *(const float4*)(trow + 64);
  const float4 t17 = *(const float4*)(trow + 68);
  const float4 t18 = *(const float4*)(trow + 72);
  const float4 t19 = *(const float4*)(trow + 76);

  const float* rb = sb0;
  float*       wb = sb1;
  #pragma unroll 1
  for (int s = 1; s <= NST; ++s) {
    // A[m] = stage-(s-1) value at word 8*tid-52+m, m = 0..51; own 8 in xp.
    float A[52];
    #pragma unroll
    for (int i = 0; i < 13; ++i) {
      const float4 v = *(const float4*)(rb + widx[i]);
      A[4*i] = v.x; A[4*i+1] = v.y; A[4*i+2] = v.z; A[4*i+3] = v.w;
    }
    float acc0[RPT], acc1[RPT];
    #pragma unroll
    for (int j = 0; j < RPT; ++j) { acc0[j] = 0.f; acc1[j] = 0.f; }
    // Lags 1..40 from named register taps.
    TAPSTEP(0,  t00) TAPSTEP(1,  t01) TAPSTEP(2,  t02) TAPSTEP(3,  t03)
    TAPSTEP(4,  t04) TAPSTEP(5,  t05) TAPSTEP(6,  t06) TAPSTEP(7,  t07)
    TAPSTEP(8,  t08) TAPSTEP(9,  t09) TAPSTEP(10, t10) TAPSTEP(11, t11)
    TAPSTEP(12, t12) TAPSTEP(13, t13) TAPSTEP(14, t14) TAPSTEP(15, t15)
    TAPSTEP(16, t16) TAPSTEP(17, t17) TAPSTEP(18, t18) TAPSTEP(19, t19)
    // Lags 41..49 from LDS (p compile-time under unroll; d1=50 slot dummy).
    #pragma unroll
    for (int p = 20; p < 25; ++p) {
      const float4 tp = *(const float4*)(trow + 4 * p);
      TAPSTEP(p, tp)
    }
    const float ia = 1.0f / (float)s;
    #pragma unroll
    for (int j = 0; j < RPT; ++j) {
      const float xn = fmaf(p0f + (float)j, acc1[j], acc0[j]) * ia;
      y[j] += xn;
      xp[j] = xn;
    }
    {
      float4 v;
      v.x = xp[0]; v.y = xp[1]; v.z = xp[2]; v.w = xp[3];
      *(float4*)(wb + sidx0) = v;
      v.x = xp[4]; v.y = xp[5]; v.z = xp[6]; v.w = xp[7];
      *(float4*)(wb + sidx1) = v;
    }
    __syncthreads();
    const float* t = rb; rb = wb; wb = (float*)t;
  }

  // Epilogue: out = y * exp(lerp(mc[...,0])). Outputs are samples >= HALO.
  if (tid >= HALO / RPT && g0 < TT) {
    const int n1 = min(n0 + 1, NFR - 1);
    const float k0 = mcb[n0 * NC];
    const float k1 = mcb[n1 * NC];
    const float dk = (k1 - k0) * (1.0f / FP);
    float* ob = out + b * TT + g0;
    #pragma unroll
    for (int k = 0; k < 2; ++k) {
      float4 v;
      #pragma unroll
      for (int e = 0; e < 4; ++e) {
        const int j = 4 * k + e;
        const float Kg = __expf(fmaf(p0f + (float)j, dk, k0));
        ((float*)&v)[e] = y[j] * Kg;
      }
      *(float4*)(ob + 4 * k) = v;
    }
  }
}

extern "C" void kernel_launch(void* const* d_in, const int* in_sizes, int n_in,
                              void* d_out, int out_size, void* d_ws, size_t ws_size,
                              hipStream_t stream) {
  const float* x  = (const float*)d_in[0];
  const float* mc = (const float*)d_in[1];
  float* out      = (float*)d_out;
  mlsa_kernel<<<NB * TILES, NT, 0, stream>>>(x, mc, out);
}

// Round 10
// 81.473 us; speedup vs baseline: 3.3405x; 2.6088x over previous
//
#include <hip/hip_runtime.h>

// MLSA-style multi-stage time-varying FIR.
// y = (sum_{n=0..20} F^n x / n!) * exp(lerp(mc[...,0]))
// F: xn[t] = sum_{d=1..49} lerp_t(mc[:, :, d]) * xa[t-d]
//
// Round-9 redesign. NT=768 is structurally incompatible with taps-in-regs:
// 12 waves/block => 3 waves/SIMD => hard HW cap 170 VGPR/wave < ~195 demand;
// and the allocator pinned 84 regardless of launch_bounds/LDS hints (R5-R9
// all spilled, FETCH 0.5-0.8 GB). New shape: NT=384 (6 waves, 1 block/CU),
// RPT=16 => 2 waves/SIMD => HW allows 256 VGPR/wave. amdgpu_waves_per_eu(1,2)
// pins the compiler's occupancy target to match. 15 named float4 taps
// (lags 1..30) in regs + 10 LDS tap reads (lags 31..49).
// Per-sample LDS: (13 window + 10 tap + 4 store)/16 = 1.7 wave-inst/sample
// (R4: 3.75) -> LDS/stage/CU ~1950 cyc << VALU ~6270 cyc. VALU-bound.

#define FO    49      // filter order (lags 1..49)
#define FP    80      // frame period
#define NST   20      // Taylor stages
#define NB    8       // batch
#define TT    160000  // samples per batch row
#define NFR   2000    // frames
#define NC    50      // coeffs per frame
#define HALO  1024    // left halo (>= 20*49=980)
#define NT    384     // threads per block (6 waves; 2,2,1,1 per SIMD)
#define RPT   16      // samples per thread (16-aligned => one frame per thread)
#define EE    6144    // NT*RPT extended region
#define TOUT  5120    // EE - HALO outputs per tile
#define TILES 32      // TT / TOUT coverage (32*5120 = 163840 >= 160000)
#define PADW  56      // zero pad words in front of data (underrun reach: 52)
#define NFRL  80      // tap rows per block (<= 78 distinct + slack)
#define TROW  100     // tap row stride in words (49 float2 + pad; 400B)

// 16B-group XOR swizzle. NOTE: swz(g+1) != swz(g)+1 in odd octets -- always
// swizzle each group address individually (round-3 bug).
__device__ __forceinline__ int swz(int g) { return g ^ ((g >> 3) & 7); }

// One tap pair (lags d0=2*PP+1, d1=2*PP+2) applied to all RPT samples.
// PP must be compile-time; branches fold under unroll.
#define TAPSTEP(PP, TP)                                                \
  {                                                                    \
    const int d0 = 2 * (PP) + 1, d1 = 2 * (PP) + 2;                    \
    _Pragma("unroll")                                                  \
    for (int j = 0; j < RPT; ++j) {                                    \
      const int ka = 52 + j - d0;                                      \
      const float va = (ka < 52) ? A[ka] : xp[ka - 52];                \
      acc0[j] = fmaf((TP).x, va, acc0[j]);                             \
      acc1[j] = fmaf((TP).y, va, acc1[j]);                             \
      if (d1 <= FO) {                                                  \
        const int kb = 52 + j - d1;                                    \
        const float vb = (kb < 52) ? A[kb] : xp[kb - 52];              \
        acc0[j] = fmaf((TP).z, vb, acc0[j]);                           \
        acc1[j] = fmaf((TP).w, vb, acc1[j]);                           \
      }                                                                \
    }                                                                  \
  }

__global__ __launch_bounds__(NT)
__attribute__((amdgpu_waves_per_eu(1, 2)))
void mlsa_kernel(
    const float* __restrict__ x, const float* __restrict__ mc,
    float* __restrict__ out) {
  __shared__ __align__(16) float sb0[PADW + EE];
  __shared__ __align__(16) float sb1[PADW + EE];
  __shared__ __align__(16) float taps[NFRL * TROW];

  const int tid  = threadIdx.x;
  const int b    = blockIdx.x >> 5;   // TILES == 32
  const int tile = blockIdx.x & 31;
  const int base = tile * TOUT - HALO;  // global sample index of local 0
  const float* __restrict__ xb  = x + b * TT;
  const float* __restrict__ mcb = mc + b * NFR * NC;

  if (tid < PADW) { sb0[tid] = 0.f; sb1[tid] = 0.f; }

  // Stage x tile into sb0 (stride-1 groups, coalesced; base%4==0, TT%4==0).
  #pragma unroll
  for (int i = 0; i < EE / 4 / NT; ++i) {
    const int q  = i * NT + tid;
    const int t0 = base + q * 4;
    float4 v = make_float4(0.f, 0.f, 0.f, 0.f);
    if (t0 >= 0 && t0 < TT) v = *(const float4*)(xb + t0);
    *(float4*)(sb0 + PADW + 4 * swz(q)) = v;
  }

  // Tap table -> LDS. Row e = frame fb+e; word 2*(d-1) = {c_d, dc_d/FP}.
  const int fb = max(base, 0) / FP;
  for (int idx = tid; idx < NFRL * FO; idx += NT) {
    const int e  = idx / FO;
    const int dm = idx - e * FO;
    const int fa = min(fb + e, NFR - 1);
    const int fn = min(fb + e + 1, NFR - 1);
    const float a0 = mcb[fa * NC + dm + 1];
    const float a1 = mcb[fn * NC + dm + 1];
    *(float2*)(taps + e * TROW + 2 * dm) = make_float2(a0, (a1 - a0) * (1.0f / FP));
  }

  // Flat map: thread owns samples 16*tid .. 16*tid+15. base%16==0 =>
  // g0%16==0 => g0 mod 80 in {0,16,32,48,64} => all 16 in ONE frame.
  const int g0 = base + RPT * tid;
  const int gc = min(max(g0, 0), TT - 1);
  const int n0 = gc / FP;
  const int fi = n0 - fb;
  const float p0f = (float)(gc - n0 * FP);

  // Window LDS group addresses (each swizzled individually): groups
  // 4*tid-13 .. 4*tid-1 cover words 16*tid-52 .. 16*tid-1; q<0 -> pad.
  int widx[13];
  #pragma unroll
  for (int i = 0; i < 13; ++i) {
    const int q = 4 * tid - 13 + i;
    widx[i] = (q < 0) ? (PADW + 4 * q) : (PADW + 4 * swz(q));
  }
  int sidx[4];
  #pragma unroll
  for (int k = 0; k < 4; ++k) sidx[k] = PADW + 4 * swz(4 * tid + k);

  // Own 16 samples; xp persists across stages (= prev stage values).
  float xp[RPT];
  #pragma unroll
  for (int k = 0; k < 4; ++k) {
    const int t0 = g0 + 4 * k;
    float4 v = make_float4(0.f, 0.f, 0.f, 0.f);
    if (t0 >= 0 && t0 < TT) v = *(const float4*)(xb + t0);
    xp[4*k] = v.x; xp[4*k+1] = v.y; xp[4*k+2] = v.z; xp[4*k+3] = v.w;
  }
  float y[RPT];
  #pragma unroll
  for (int j = 0; j < RPT; ++j) y[j] = xp[j];

  __syncthreads();

  // Taps for lags 1..30 in 15 NAMED float4s; lags 31..49 from LDS per stage.
  const float* trow = taps + fi * TROW;
  const float4 t00 = *(const float4*)(trow +  0);
  const float4 t01 = *(const float4*)(trow +  4);
  const float4 t02 = *(const float4*)(trow +  8);
  const float4 t03 = *(const float4*)(trow + 12);
  const float4 t04 = *(const float4*)(trow + 16);
  const float4 t05 = *(const float4*)(trow + 20);
  const float4 t06 = *(const float4*)(trow + 24);
  const float4 t07 = *(const float4*)(trow + 28);
  const float4 t08 = *(const float4*)(trow + 32);
  const float4 t09 = *(const float4*)(trow + 36);
  const float4 t10 = *(const float4*)(trow + 40);
  const float4 t11 = *(const float4*)(trow + 44);
  const float4 t12 = *(const float4*)(trow + 48);
  const float4 t13 = *(const float4*)(trow + 52);
  const float4 t14 = *(const float4*)(trow + 56);

  const float* rb = sb0;
  float*       wb = sb1;
  #pragma unroll 1
  for (int s = 1; s <= NST; ++s) {
    // A[m] = stage-(s-1) value at word 16*tid-52+m, m = 0..51; own 16 in xp.
    float A[52];
    #pragma unroll
    for (int i = 0; i < 13; ++i) {
      const float4 v = *(const float4*)(rb + widx[i]);
      A[4*i] = v.x; A[4*i+1] = v.y; A[4*i+2] = v.z; A[4*i+3] = v.w;
    }
    float acc0[RPT], acc1[RPT];
    #pragma unroll
    for (int j = 0; j < RPT; ++j) { acc0[j] = 0.f; acc1[j] = 0.f; }
    // Lags 1..30 from named register taps.
    TAPSTEP(0,  t00) TAPSTEP(1,  t01) TAPSTEP(2,  t02) TAPSTEP(3,  t03)
    TAPSTEP(4,  t04) TAPSTEP(5,  t05) TAPSTEP(6,  t06) TAPSTEP(7,  t07)
    TAPSTEP(8,  t08) TAPSTEP(9,  t09) TAPSTEP(10, t10) TAPSTEP(11, t11)
    TAPSTEP(12, t12) TAPSTEP(13, t13) TAPSTEP(14, t14)
    // Lags 31..49 from LDS (p compile-time under unroll; d1=50 slot dummy).
    #pragma unroll
    for (int p = 15; p < 25; ++p) {
      const float4 tp = *(const float4*)(trow + 4 * p);
      TAPSTEP(p, tp)
    }
    const float ia = 1.0f / (float)s;
    #pragma unroll
    for (int j = 0; j < RPT; ++j) {
      const float xn = fmaf(p0f + (float)j, acc1[j], acc0[j]) * ia;
      y[j] += xn;
      xp[j] = xn;
    }
    #pragma unroll
    for (int k = 0; k < 4; ++k) {
      float4 v;
      v.x = xp[4*k]; v.y = xp[4*k+1]; v.z = xp[4*k+2]; v.w = xp[4*k+3];
      *(float4*)(wb + sidx[k]) = v;
    }
    __syncthreads();
    const float* t = rb; rb = wb; wb = (float*)t;
  }

  // Epilogue: out = y * exp(lerp(mc[...,0])). Outputs are samples >= HALO.
  if (tid >= HALO / RPT && g0 < TT) {
    const int n1 = min(n0 + 1, NFR - 1);
    const float k0 = mcb[n0 * NC];
    const float k1 = mcb[n1 * NC];
    const float dk = (k1 - k0) * (1.0f / FP);
    float* ob = out + b * TT + g0;
    #pragma unroll
    for (int k = 0; k < 4; ++k) {
      float4 v;
      #pragma unroll
      for (int e = 0; e < 4; ++e) {
        const int j = 4 * k + e;
        const float Kg = __expf(fmaf(p0f + (float)j, dk, k0));
        ((float*)&v)[e] = y[j] * Kg;
      }
      *(float4*)(ob + 4 * k) = v;
    }
  }
}

extern "C" void kernel_launch(void* const* d_in, const int* in_sizes, int n_in,
                              void* d_out, int out_size, void* d_ws, size_t ws_size,
                              hipStream_t stream) {
  const float* x  = (const float*)d_in[0];
  const float* mc = (const float*)d_in[1];
  float* out      = (float*)d_out;
  mlsa_kernel<<<NB * TILES, NT, 0, stream>>>(x, mc, out);
}